// Round 2
// baseline (1025.871 us; speedup 1.0000x reference)
//
#include <hip/hip_runtime.h>

// DGM forward, MI355X. bf16 MFMA (16x16x32), fp32 accum, fp32 tanh.
// R2: M=64 rows/WG, 256 threads (4 waves; wave w: cols [w*64,w*64+64), rows 0..63).
// SRb eliminated via zs = Z*S_old trick -> LDS = Sb + S1b = 64KB -> 2 WGs/CU.
// 4 barriers/layer. zs packed bf16 to keep VGPR < 256.
//
// MFMA 16x16x32 layouts (ln = lane 0..63, q = ln>>4, c15 = ln&15):
//  A-frag: lane holds A[m=c15][k=kb*32+q*8+i], i=0..7
//  B-frag: lane holds B[k=kb*32+q*8+i][n=c*16+c15]
//  C/D:    lane holds C[row=q*4+ii][col=c15]
// W pre-packed in d_ws in B-frag order: idx = (((cblk*8+kb)*64+ln)*8+i)
// LDS state swizzle: elem(r,k) -> r*256 + (((k>>3)^r)&31)*8 + (k&7)

typedef __attribute__((ext_vector_type(8))) short bf16x8;
typedef __attribute__((ext_vector_type(4))) float f32x4;

__device__ __forceinline__ short f2bf(float f) {
    unsigned u = __float_as_uint(f);
    unsigned r = (u + 0x7FFFu + ((u >> 16) & 1u)) >> 16;
    return (short)r;
}
__device__ __forceinline__ float bf2f(short h) {
    return __uint_as_float(((unsigned)(unsigned short)h) << 16);
}
__device__ __forceinline__ float fast_tanh(float x) {
    float e = __expf(2.0f * x);
    return 1.0f - 2.0f * __builtin_amdgcn_rcpf(e + 1.0f);
}
__device__ __forceinline__ int sw_off(int r, int k) {
    return r * 256 + ((((k >> 3) ^ r) & 31) << 3) + (k & 7);
}
__device__ __forceinline__ unsigned pk2(float a, float b) {
    return (unsigned)(unsigned short)f2bf(a) | ((unsigned)(unsigned short)f2bf(b) << 16);
}
__device__ __forceinline__ float upk(unsigned p, int hi) {
    return __uint_as_float(hi ? (p & 0xFFFF0000u) : (p << 16));
}

// ---------------- pack weights fp32 -> bf16, B-fragment order ----------------
__global__ void pack_w(const float* __restrict__ Wz, const float* __restrict__ Wg,
                       const float* __restrict__ Wr, const float* __restrict__ Wh,
                       short* __restrict__ out) {
    int idx = blockIdx.x * 256 + threadIdx.x;   // 12*65536 threads
    int mat = idx >> 16;                        // 0..11 = l*4+g
    int e   = idx & 65535;
    int l = mat >> 2, g = mat & 3;
    int i  = e & 7;
    int ln = (e >> 3) & 63;
    int kb = (e >> 9) & 7;
    int c  = e >> 12;
    int k = kb * 32 + (ln >> 4) * 8 + i;
    int n = c * 16 + (ln & 15);
    const float* W = (g == 0) ? Wz : (g == 1) ? Wg : (g == 2) ? Wr : Wh;
    out[idx] = f2bf(W[l * 65536 + k * 256 + n]);
}

// ---------------- one gate GEMM: acc = bias + X@U + In@W ----------------
__device__ __forceinline__ void gate_gemm(const short* __restrict__ In,   // LDS, swizzled [64][256]
                                          const short* __restrict__ Wm,   // packed bf16 65536
                                          const float* __restrict__ U,    // [2][256]
                                          const float* __restrict__ bias, // [256]
                                          const float2* __restrict__ txS, // LDS [64]
                                          int q, int c15, int w, int ln,
                                          f32x4 acc[4][4]) {
    float2 tx[4][4];
#pragma unroll
    for (int rb = 0; rb < 4; rb++)
#pragma unroll
        for (int ii = 0; ii < 4; ii++) tx[rb][ii] = txS[rb * 16 + q * 4 + ii];
#pragma unroll
    for (int cb = 0; cb < 4; cb++) {
        int col = (w * 4 + cb) * 16 + c15;
        float u0 = U[col], u1 = U[256 + col], bb = bias[col];
#pragma unroll
        for (int rb = 0; rb < 4; rb++)
#pragma unroll
            for (int ii = 0; ii < 4; ii++)
                acc[rb][cb][ii] = bb + tx[rb][ii].x * u0 + tx[rb][ii].y * u1;
    }
#pragma unroll
    for (int kb = 0; kb < 8; kb++) {
        bf16x8 a[4];
#pragma unroll
        for (int rb = 0; rb < 4; rb++) {
            int r = rb * 16 + c15;
            a[rb] = *(const bf16x8*)(In + r * 256 + ((((kb * 4 + q) ^ r) & 31) << 3));
        }
#pragma unroll
        for (int cb = 0; cb < 4; cb++) {
            bf16x8 b = *(const bf16x8*)(Wm + ((((w * 4 + cb) * 8 + kb) * 64 + ln) << 3));
#pragma unroll
            for (int rb = 0; rb < 4; rb++)
                acc[rb][cb] = __builtin_amdgcn_mfma_f32_16x16x32_bf16(a[rb], b, acc[rb][cb], 0, 0, 0);
        }
    }
}

// ---------------- main kernel: 64 rows per WG, 256 threads ----------------
__launch_bounds__(256, 2)
__global__ void dgm_main(const float* __restrict__ T, const float* __restrict__ X,
                         const float* __restrict__ W0, const float* __restrict__ b0,
                         const float* __restrict__ Uz, const float* __restrict__ Ug,
                         const float* __restrict__ Ur, const float* __restrict__ Uh,
                         const float* __restrict__ bz, const float* __restrict__ bg,
                         const float* __restrict__ br, const float* __restrict__ bh,
                         const float* __restrict__ Wf, const float* __restrict__ bfp,
                         const short* __restrict__ Wp, float* __restrict__ out) {
    __shared__ __align__(16) short Sb[16384];    // 32 KB, S (also holds S*R mid-layer)
    __shared__ __align__(16) short S1b[16384];   // 32 KB, S1 (immutable after init)
    __shared__ float2 txS[64];

    const int tid = threadIdx.x;
    const int w   = tid >> 6;
    const int ln  = tid & 63;
    const int q   = ln >> 4;
    const int c15 = ln & 15;
    const int m0  = blockIdx.x * 64;

    if (tid < 64) txS[tid] = make_float2(T[m0 + tid], X[m0 + tid]);
    __syncthreads();

    // ---- S1 = tanh(X@W0 + b0); S = S1.  One column per thread, 64 rows. ----
    {
        float w00 = W0[tid], w01 = W0[256 + tid], bb = b0[tid];
#pragma unroll 4
        for (int r = 0; r < 64; r++) {
            float2 tx = txS[r];
            short v = f2bf(fast_tanh(tx.x * w00 + tx.y * w01 + bb));
            int off = sw_off(r, tid);
            S1b[off] = v;
            Sb[off]  = v;
        }
    }
    __syncthreads();

    // ---- layers ----
    for (int l = 0; l < 3; l++) {
        const short* Wzp = Wp + (l * 4 + 0) * 65536;
        const short* Wgp = Wp + (l * 4 + 1) * 65536;
        const short* Wrp = Wp + (l * 4 + 2) * 65536;
        const short* Whp = Wp + (l * 4 + 3) * 65536;

        // Z and R gates (both read Sb)
        unsigned zsp[4][4][2], srp[4][4][2];
        {
            f32x4 zacc[4][4], racc[4][4];
            gate_gemm(Sb, Wzp, Uz + l * 512, bz + l * 256, txS, q, c15, w, ln, zacc);
            gate_gemm(Sb, Wrp, Ur + l * 512, br + l * 256, txS, q, c15, w, ln, racc);
#pragma unroll
            for (int rb = 0; rb < 4; rb++)
#pragma unroll
                for (int cb = 0; cb < 4; cb++) {
                    float zs[4], sr[4];
#pragma unroll
                    for (int ii = 0; ii < 4; ii++) {
                        int off = sw_off(rb * 16 + q * 4 + ii, (w * 4 + cb) * 16 + c15);
                        float s = bf2f(Sb[off]);
                        float z = fast_tanh(zacc[rb][cb][ii]);
                        float r = fast_tanh(racc[rb][cb][ii]);
                        zs[ii] = z * s;    // Z*S_old, survives the Sb overwrite
                        sr[ii] = s * r;    // S_old*R -> new Sb contents
                    }
                    zsp[rb][cb][0] = pk2(zs[0], zs[1]); zsp[rb][cb][1] = pk2(zs[2], zs[3]);
                    srp[rb][cb][0] = pk2(sr[0], sr[1]); srp[rb][cb][1] = pk2(sr[2], sr[3]);
                }
        }
        __syncthreads();   // B1: all Sb reads (Z,R gemms + elementwise) done
#pragma unroll
        for (int rb = 0; rb < 4; rb++)
#pragma unroll
            for (int cb = 0; cb < 4; cb++)
#pragma unroll
                for (int ii = 0; ii < 4; ii++) {
                    int off = sw_off(rb * 16 + q * 4 + ii, (w * 4 + cb) * 16 + c15);
                    Sb[off] = (short)(srp[rb][cb][ii >> 1] >> ((ii & 1) * 16));
                }

        // G gate (reads only S1b) — overlaps the barrier window
        f32x4 gm[4][4];
        gate_gemm(S1b, Wgp, Ug + l * 512, bg + l * 256, txS, q, c15, w, ln, gm);
#pragma unroll
        for (int rb = 0; rb < 4; rb++)
#pragma unroll
            for (int cb = 0; cb < 4; cb++)
#pragma unroll
                for (int ii = 0; ii < 4; ii++)
                    gm[rb][cb][ii] = 1.0f - fast_tanh(gm[rb][cb][ii]);   // (1-G)
        __syncthreads();   // B2: SR visible in Sb

        // H gate (reads Sb = S*R)
        f32x4 hacc[4][4];
        gate_gemm(Sb, Whp, Uh + l * 512, bh + l * 256, txS, q, c15, w, ln, hacc);

        unsigned snp[4][4][2];
#pragma unroll
        for (int rb = 0; rb < 4; rb++)
#pragma unroll
            for (int cb = 0; cb < 4; cb++) {
                float sn[4];
#pragma unroll
                for (int ii = 0; ii < 4; ii++) {
                    float h = fast_tanh(hacc[rb][cb][ii]);
                    float zs = upk(zsp[rb][cb][ii >> 1], ii & 1);
                    sn[ii] = gm[rb][cb][ii] * h + zs;   // (1-G)*H + Z*S_old
                }
                snp[rb][cb][0] = pk2(sn[0], sn[1]); snp[rb][cb][1] = pk2(sn[2], sn[3]);
            }
        __syncthreads();   // B3: all H-gemm reads of Sb done
#pragma unroll
        for (int rb = 0; rb < 4; rb++)
#pragma unroll
            for (int cb = 0; cb < 4; cb++)
#pragma unroll
                for (int ii = 0; ii < 4; ii++) {
                    int off = sw_off(rb * 16 + q * 4 + ii, (w * 4 + cb) * 16 + c15);
                    Sb[off] = (short)(snp[rb][cb][ii >> 1] >> ((ii & 1) * 16));
                }
        __syncthreads();   // B4: new S visible
    }

    // ---- out = S @ Wf + bf : 4 threads per row, 64 cols each ----
    {
        int row = tid >> 2;
        int seg = tid & 3;
        float sum = 0.0f;
#pragma unroll 8
        for (int kk = 0; kk < 64; kk++) {
            int k = seg * 64 + kk;
            sum += bf2f(Sb[sw_off(row, k)]) * Wf[k];
        }
        sum += __shfl_down(sum, 2, 4);
        sum += __shfl_down(sum, 1, 4);
        if (seg == 0) out[m0 + row] = sum + bfp[0];
    }
}

extern "C" void kernel_launch(void* const* d_in, const int* in_sizes, int n_in,
                              void* d_out, int out_size, void* d_ws, size_t ws_size,
                              hipStream_t stream) {
    const float* T  = (const float*)d_in[0];
    const float* X  = (const float*)d_in[1];
    const float* W0 = (const float*)d_in[2];
    const float* b0 = (const float*)d_in[3];
    const float* Uz = (const float*)d_in[4];
    const float* Ug = (const float*)d_in[5];
    const float* Ur = (const float*)d_in[6];
    const float* Uh = (const float*)d_in[7];
    const float* Wz = (const float*)d_in[8];
    const float* Wg = (const float*)d_in[9];
    const float* Wr = (const float*)d_in[10];
    const float* Wh = (const float*)d_in[11];
    const float* bz = (const float*)d_in[12];
    const float* bg = (const float*)d_in[13];
    const float* br = (const float*)d_in[14];
    const float* bh = (const float*)d_in[15];
    const float* Wf = (const float*)d_in[16];
    const float* bfp= (const float*)d_in[17];
    float* out = (float*)d_out;
    short* Wp = (short*)d_ws;           // 12*65536 bf16 = 1.5 MB
    const int N = in_sizes[0];

    pack_w<<<(12 * 65536) / 256, 256, 0, stream>>>(Wz, Wg, Wr, Wh, Wp);
    dgm_main<<<N / 64, 256, 0, stream>>>(T, X, W0, b0, Uz, Ug, Ur, Uh,
                                         bz, bg, br, bh, Wf, bfp, Wp, out);
}